// Round 2
// baseline (2716.582 us; speedup 1.0000x reference)
//
#include <hip/hip_runtime.h>
#include <hip/hip_bf16.h>

#define HW   128
#define HW2  16384   // 128*128

// ---------------- prep: weights -> transposed [ci][co][9] per layer ------------
// Layer l<6 at Wt + l*36864 (64ci*64co*9); layer 6 at Wt + 221184 (64ci*36co*9).
__global__ void prep_weights(const float* __restrict__ w0,
                             const float* __restrict__ wm,
                             const float* __restrict__ wl,
                             float* __restrict__ Wt)
{
    int idx = blockIdx.x * 256 + threadIdx.x;
    if (idx >= 241920) return;
    if (idx < 221184) {
        int l = idx / 36864, r = idx % 36864;
        int ci = r / 576, c2 = r % 576, co = c2 / 9, k = c2 % 9;
        const float* src = (l == 0) ? w0 : (wm + (size_t)(l - 1) * 36864);
        Wt[idx] = src[(co * 64 + ci) * 9 + k];
    } else {
        int r = idx - 221184;
        int ci = r / 324, c2 = r % 324, co = c2 / 9, k = c2 % 9;
        Wt[idx] = wl[(co * 64 + ci) * 9 + k];
    }
}

// ---------------- prep: fold bias + BN into per-channel A (scale), B (shift) ----
__global__ void prep_ab(const float* b0, const float* g0, const float* be0,
                        const float* m0, const float* v0,
                        const float* bm, const float* gm, const float* bem,
                        const float* mm, const float* vm,
                        const float* bl, const float* gl, const float* bel,
                        const float* ml, const float* vl,
                        float* __restrict__ Af, float* __restrict__ Bf)
{
    int idx = blockIdx.x * 256 + threadIdx.x;
    if (idx >= 448) return;
    int l = idx >> 6, c = idx & 63;
    float b, g, be, m, v;
    if (l == 0) {
        b = b0[c]; g = g0[c]; be = be0[c]; m = m0[c]; v = v0[c];
    } else if (l < 6) {
        int o = (l - 1) * 64 + c;
        b = bm[o]; g = gm[o]; be = bem[o]; m = mm[o]; v = vm[o];
    } else {
        if (c >= 36) { Af[idx] = 0.f; Bf[idx] = 0.f; return; }
        b = bl[c]; g = gl[c]; be = bel[c]; m = ml[c]; v = vl[c];
    }
    float s = g / sqrtf(v + 1e-5f);
    Af[idx] = s;
    Bf[idx] = (b - m) * s + be;
}

// ---------------- conv 3x3 SAME + BN + tanh -----------------------------------
// grid (W/32, H/8, N), block 256 = 8x32 pixels, 1 px/thread, COUT accumulators.
// Input staged in LDS fp32, 32 input channels per half (43.5 KB).
template<int COUT>
__global__ __launch_bounds__(256)
void conv_bn_tanh(const float* __restrict__ src, const float* __restrict__ Wt,
                  const float* __restrict__ A, const float* __restrict__ B,
                  float* __restrict__ dst)
{
    __shared__ float tile[32 * 10 * 34];
    const int n = blockIdx.z;
    const int h0 = blockIdx.y * 8, w0 = blockIdx.x * 32;
    const float* sp = src + (size_t)n * 64 * HW2;
    const int t = threadIdx.x;
    const int tw = t & 31, th = t >> 5;

    float acc[COUT];
#pragma unroll
    for (int i = 0; i < COUT; ++i) acc[i] = 0.f;

    for (int half = 0; half < 2; ++half) {
        if (half) __syncthreads();            // finish compute(half0) before reload
        for (int idx = t; idx < 32 * 340; idx += 256) {
            int ci = idx / 340, r = idx % 340, y = r / 34, xw = r % 34;
            int gy = h0 + y - 1, gx = w0 + xw - 1;
            float v = 0.f;
            if ((unsigned)gy < 128u && (unsigned)gx < 128u)
                v = sp[(size_t)(half * 32 + ci) * HW2 + gy * 128 + gx];
            tile[idx] = v;
        }
        __syncthreads();

        const float* wbase = Wt + (size_t)half * 32 * COUT * 9;
#pragma unroll 1
        for (int ci = 0; ci < 32; ++ci) {
            float xv[9];
#pragma unroll
            for (int ky = 0; ky < 3; ++ky)
#pragma unroll
                for (int kx = 0; kx < 3; ++kx)
                    xv[ky * 3 + kx] = tile[ci * 340 + (th + ky) * 34 + (tw + kx)];
            const float* wp = wbase + ci * COUT * 9;   // block-uniform -> s_load
#pragma unroll
            for (int co = 0; co < COUT; ++co) {
                float s = acc[co];
#pragma unroll
                for (int k = 0; k < 9; ++k) s = fmaf(xv[k], wp[co * 9 + k], s);
                acc[co] = s;
            }
        }
    }

    const int h = h0 + th, w = w0 + tw;
    float* dp = dst + (size_t)n * COUT * HW2 + h * 128 + w;
#pragma unroll
    for (int co = 0; co < COUT; ++co) {
        float y = fmaf(acc[co], A[co], B[co]);
        dp[(size_t)co * HW2] = tanhf(y);
    }
}

// ---------------- dynamic conv: coef = h7·bases; out = coef · patches(x) -------
// grid (4,16,8), block 256 = 8x32 pixels. x staged fp32 in two 32-ch halves.
__global__ __launch_bounds__(256)
void dyn_conv(const float* __restrict__ x, const float* __restrict__ h7,
              const float* __restrict__ bases, float* __restrict__ out)
{
    __shared__ float tile[32 * 10 * 34];
    const int n = blockIdx.z;
    const int h0 = blockIdx.y * 8, w0 = blockIdx.x * 32;
    const float* xp = x + (size_t)n * 64 * HW2;
    const int t = threadIdx.x;
    const int tw = t & 31, th = t >> 5;
    const int h = h0 + th, w = w0 + tw;

    float bs[54];
#pragma unroll
    for (int i = 0; i < 54; ++i) bs[i] = bases[i];    // [k][l], block-uniform

    float coef[54];   // [m][l]
#pragma unroll
    for (int i = 0; i < 54; ++i) coef[i] = 0.f;

    const float* hp = h7 + (size_t)n * 36 * HW2 + h * 128 + w;
#pragma unroll
    for (int m = 0; m < 6; ++m)
#pragma unroll
        for (int k = 0; k < 6; ++k) {
            float f = hp[(size_t)(m * 6 + k) * HW2];
#pragma unroll
            for (int l = 0; l < 9; ++l)
                coef[m * 9 + l] = fmaf(f, bs[k * 9 + l], coef[m * 9 + l]);
        }

    float* op = out + (size_t)n * 384 * HW2 + h * 128 + w;

    for (int half = 0; half < 2; ++half) {
        if (half) __syncthreads();            // finish compute(half0) before reload
        for (int idx = t; idx < 32 * 340; idx += 256) {
            int ci = idx / 340, r = idx % 340, y = r / 34, xw = r % 34;
            int gy = h0 + y - 1, gx = w0 + xw - 1;
            float v = 0.f;
            if ((unsigned)gy < 128u && (unsigned)gx < 128u)
                v = xp[(size_t)(half * 32 + ci) * HW2 + gy * 128 + gx];
            tile[idx] = v;
        }
        __syncthreads();

#pragma unroll 1
        for (int c = 0; c < 32; ++c) {
            float xv[9];
#pragma unroll
            for (int ky = 0; ky < 3; ++ky)
#pragma unroll
                for (int kx = 0; kx < 3; ++kx)
                    xv[ky * 3 + kx] = tile[c * 340 + (th + ky) * 34 + (tw + kx)];
            int cg = half * 32 + c;
#pragma unroll
            for (int m = 0; m < 6; ++m) {
                float s = 0.f;
#pragma unroll
                for (int l = 0; l < 9; ++l) s = fmaf(coef[m * 9 + l], xv[l], s);
                op[(size_t)(cg * 6 + m) * HW2] = s;
            }
        }
    }
}

// ---------------- launch -------------------------------------------------------
extern "C" void kernel_launch(void* const* d_in, const int* in_sizes, int n_in,
                              void* d_out, int out_size, void* d_ws, size_t ws_size,
                              hipStream_t stream)
{
    const float* x   = (const float*)d_in[0];
    const float* w0  = (const float*)d_in[1];
    const float* b0  = (const float*)d_in[2];
    const float* g0  = (const float*)d_in[3];
    const float* be0 = (const float*)d_in[4];
    const float* m0  = (const float*)d_in[5];
    const float* v0  = (const float*)d_in[6];
    const float* wm  = (const float*)d_in[7];
    const float* bm  = (const float*)d_in[8];
    const float* gm  = (const float*)d_in[9];
    const float* bem = (const float*)d_in[10];
    const float* mm  = (const float*)d_in[11];
    const float* vm  = (const float*)d_in[12];
    const float* wl  = (const float*)d_in[13];
    const float* bl  = (const float*)d_in[14];
    const float* gl  = (const float*)d_in[15];
    const float* bel = (const float*)d_in[16];
    const float* ml  = (const float*)d_in[17];
    const float* vl  = (const float*)d_in[18];
    const float* bas = (const float*)d_in[19];

    float* Wt = (float*)d_ws;           // 241920 floats
    float* Af = Wt + 241920;            // 448
    float* Bf = Af + 448;               // 448
    float* buf0 = (float*)((char*)d_ws + (1 << 20));
    float* buf1 = buf0 + (size_t)8 * 64 * HW2;   // 33.55 MB each

    dim3 cgrid(4, 16, 8);   // (W/32, H/8, N)

    prep_weights<<<945, 256, 0, stream>>>(w0, wm, wl, Wt);
    prep_ab<<<2, 256, 0, stream>>>(b0, g0, be0, m0, v0,
                                   bm, gm, bem, mm, vm,
                                   bl, gl, bel, ml, vl, Af, Bf);

    conv_bn_tanh<64><<<cgrid, 256, 0, stream>>>(x,    Wt,              Af,       Bf,       buf0);
    conv_bn_tanh<64><<<cgrid, 256, 0, stream>>>(buf0, Wt + 1 * 36864, Af + 64,  Bf + 64,  buf1);
    conv_bn_tanh<64><<<cgrid, 256, 0, stream>>>(buf1, Wt + 2 * 36864, Af + 128, Bf + 128, buf0);
    conv_bn_tanh<64><<<cgrid, 256, 0, stream>>>(buf0, Wt + 3 * 36864, Af + 192, Bf + 192, buf1);
    conv_bn_tanh<64><<<cgrid, 256, 0, stream>>>(buf1, Wt + 4 * 36864, Af + 256, Bf + 256, buf0);
    conv_bn_tanh<64><<<cgrid, 256, 0, stream>>>(buf0, Wt + 5 * 36864, Af + 320, Bf + 320, buf1);
    conv_bn_tanh<36><<<cgrid, 256, 0, stream>>>(buf1, Wt + 221184,    Af + 384, Bf + 384, buf0);

    dyn_conv<<<cgrid, 256, 0, stream>>>(x, buf0, bas, (float*)d_out);
}

// Round 3
// 494.747 us; speedup vs baseline: 5.4908x; 5.4908x over previous
//
#include <hip/hip_runtime.h>
#include <hip/hip_bf16.h>

typedef short bf16x4 __attribute__((ext_vector_type(4)));
typedef short bf16x8 __attribute__((ext_vector_type(8)));
typedef float f32x4  __attribute__((ext_vector_type(4)));

__device__ inline unsigned short f2us(float f) {
    __hip_bfloat16 h = __float2bfloat16(f);
    return *(unsigned short*)&h;
}
__device__ inline float us2f(unsigned short u) {
    union { unsigned int i; float f; } c; c.i = ((unsigned int)u) << 16; return c.f;
}
__device__ inline float tanh_fast(float x) {
    float xs = fminf(fmaxf(x, -20.f), 20.f);
    float t = __expf(2.f * xs);
    return 1.f - 2.f / (t + 1.f);
}

// ---------------- prep: x fp32 NCHW -> bf16 channel-last [n][h][w][c] ----------
__global__ __launch_bounds__(256) void prep_x(const float* __restrict__ x,
                                              unsigned short* __restrict__ xcl)
{
    __shared__ unsigned short t2[128 * 68];
    int bid = blockIdx.x;           // n*128 + h
    int n = bid >> 7, h = bid & 127;
    const float* xp = x + (size_t)n * 64 * 16384 + h * 128;
    int t = threadIdx.x;
    for (int i = t; i < 8192; i += 256) {
        int ci = i >> 7, w = i & 127;
        t2[w * 68 + ci] = f2us(xp[(size_t)ci * 16384 + w]);
    }
    __syncthreads();
    unsigned short* op = xcl + ((size_t)(n * 16384 + h * 128)) * 64;
    for (int i = t; i < 1024; i += 256) {
        int w = i >> 3, c8 = i & 7;
        union { bf16x4 v[2]; uint4 q; } u;
        u.v[0] = *(bf16x4*)&t2[w * 68 + c8 * 8];
        u.v[1] = *(bf16x4*)&t2[w * 68 + c8 * 8 + 4];
        *(uint4*)(op + w * 64 + c8 * 8) = u.q;
    }
}

// ---------------- prep: weights -> MFMA B-fragment order, bf16 ------------------
// Layer l: 36864 ushorts at Wf + l*36864.
// idx within layer: ((((t*2+hh)*4+nb)*64 + lane)*8 + j)
// element: ci = hh*32 + (lane>>4)*8 + j ; co = nb*16 + (lane&15) ; W[co][ci][tap]
__global__ void prep_wf(const float* __restrict__ w0, const float* __restrict__ wm,
                        const float* __restrict__ wl, unsigned short* __restrict__ Wf)
{
    int idx = blockIdx.x * 256 + threadIdx.x;
    if (idx >= 258048) return;
    int l = idx / 36864, r = idx - l * 36864;
    int tp = r >> 12, r2 = r & 4095;
    int hh = r2 >> 11, nb = (r2 >> 9) & 3, ln = (r2 >> 3) & 63, j = r2 & 7;
    int ci = hh * 32 + (ln >> 4) * 8 + j;
    int co = nb * 16 + (ln & 15);
    float val = 0.f;
    if (l < 6) {
        const float* src = (l == 0) ? w0 : (wm + (size_t)(l - 1) * 36864);
        val = src[(co * 64 + ci) * 9 + tp];
    } else if (co < 36) {
        val = wl[(co * 64 + ci) * 9 + tp];
    }
    Wf[idx] = f2us(val);
}

// ---------------- prep: fold bias + BN into per-channel A (scale), B (shift) ----
__global__ void prep_ab(const float* b0, const float* g0, const float* be0,
                        const float* m0, const float* v0,
                        const float* bm, const float* gm, const float* bem,
                        const float* mm, const float* vm,
                        const float* bl, const float* gl, const float* bel,
                        const float* ml, const float* vl,
                        float* __restrict__ Af, float* __restrict__ Bf)
{
    int idx = blockIdx.x * 256 + threadIdx.x;
    if (idx >= 448) return;
    int l = idx >> 6, c = idx & 63;
    float b, g, be, m, v;
    if (l == 0) {
        b = b0[c]; g = g0[c]; be = be0[c]; m = m0[c]; v = v0[c];
    } else if (l < 6) {
        int o = (l - 1) * 64 + c;
        b = bm[o]; g = gm[o]; be = bem[o]; m = mm[o]; v = vm[o];
    } else {
        if (c >= 36) { Af[idx] = 0.f; Bf[idx] = 0.f; return; }
        b = bl[c]; g = gl[c]; be = bel[c]; m = ml[c]; v = vl[c];
    }
    float s = g / sqrtf(v + 1e-5f);
    Af[idx] = s;
    Bf[idx] = (b - m) * s + be;
}

// ---------------- conv 3x3 + BN + tanh via MFMA implicit GEMM -------------------
// grid (8,8,8) = (w/16, h/16, n); block 256 = 4 waves.
// Block tile: 16x16 px, all 64 ci staged in LDS (18x18 halo, pad 68 -> 2-way banks).
// Wave w handles pixel rows 4w..4w+3 (M-tiles of 16 px along x), all 64 co.
__global__ __launch_bounds__(256)
void conv_mfma(const unsigned short* __restrict__ src,
               const unsigned short* __restrict__ Wf,
               const float* __restrict__ A, const float* __restrict__ B,
               unsigned short* __restrict__ dst)
{
    __shared__ unsigned short tile[18 * 18 * 68];   // 44064 B
    const int n = blockIdx.z;
    const int h0 = blockIdx.y * 16, w0 = blockIdx.x * 16;
    const int t = threadIdx.x;
    const size_t ibase = (size_t)n * 16384 * 64;

    // stage 18x18 px x 64 ci (bf16), 8 B units
    for (int i = t; i < 5184; i += 256) {
        int p = i >> 4, c4 = i & 15;
        int ty = p / 18, tx = p - ty * 18;
        int gy = h0 + ty - 1, gx = w0 + tx - 1;
        uint2 v = make_uint2(0u, 0u);
        if ((unsigned)gy < 128u && (unsigned)gx < 128u)
            v = *(const uint2*)(src + ibase + (size_t)(gy * 128 + gx) * 64 + c4 * 4);
        *(uint2*)&tile[p * 68 + c4 * 4] = v;
    }
    __syncthreads();

    const int ln = t & 63, wv = t >> 6;
    const int xln = ln & 15, qd = ln >> 4;

    f32x4 acc[4][4];
#pragma unroll
    for (int mt = 0; mt < 4; ++mt)
#pragma unroll
        for (int nb = 0; nb < 4; ++nb)
            acc[mt][nb] = (f32x4){0.f, 0.f, 0.f, 0.f};

    const uint4* wf4 = (const uint4*)Wf;
#pragma unroll
    for (int tp = 0; tp < 9; ++tp) {
        const int ky = tp / 3, kx = tp % 3;
        bf16x8 b[2][4];
#pragma unroll
        for (int hh = 0; hh < 2; ++hh)
#pragma unroll
            for (int nb = 0; nb < 4; ++nb) {
                uint4 q = wf4[((tp * 2 + hh) * 4 + nb) * 64 + ln];
                b[hh][nb] = *(bf16x8*)&q;
            }
#pragma unroll
        for (int mt = 0; mt < 4; ++mt) {
            const int off0 = ((wv * 4 + mt + ky) * 18 + xln + kx) * 68 + qd * 8;
#pragma unroll
            for (int hh = 0; hh < 2; ++hh) {
                union { bf16x8 v8; bf16x4 v4[2]; } a;
                a.v4[0] = *(const bf16x4*)&tile[off0 + hh * 32];
                a.v4[1] = *(const bf16x4*)&tile[off0 + hh * 32 + 4];
#pragma unroll
                for (int nb = 0; nb < 4; ++nb)
                    acc[mt][nb] = __builtin_amdgcn_mfma_f32_16x16x32_bf16(
                        a.v8, b[hh][nb], acc[mt][nb], 0, 0, 0);
            }
        }
    }

    // epilogue: BN + tanh -> bf16 channel-last
#pragma unroll
    for (int mt = 0; mt < 4; ++mt) {
        const int gy = h0 + wv * 4 + mt;
        unsigned short* dp = dst + ibase + (size_t)(gy * 128) * 64;
#pragma unroll
        for (int nb = 0; nb < 4; ++nb) {
            const int co = nb * 16 + xln;
            const float As = A[co], Bs = B[co];
#pragma unroll
            for (int r = 0; r < 4; ++r) {
                const int gx = w0 + qd * 4 + r;
                float y = tanh_fast(fmaf(acc[mt][nb][r], As, Bs));
                dp[(size_t)gx * 64 + co] = f2us(y);
            }
        }
    }
}

// ---------------- dynamic conv: coef = h7·bases; out = coef · patches(x) -------
// grid (4,16,8), block 256 = 8x32 px. h7 is bf16 channel-last (64-stride, 36 used).
__global__ __launch_bounds__(256)
void dyn_conv(const float* __restrict__ x, const unsigned short* __restrict__ h7,
              const float* __restrict__ bases, float* __restrict__ out)
{
    __shared__ float tile[32 * 10 * 34];
    const int n = blockIdx.z;
    const int h0 = blockIdx.y * 8, w0 = blockIdx.x * 32;
    const float* xp = x + (size_t)n * 64 * 16384;
    const int t = threadIdx.x;
    const int tw = t & 31, th = t >> 5;
    const int h = h0 + th, w = w0 + tw;

    float bs[54];
#pragma unroll
    for (int i = 0; i < 54; ++i) bs[i] = bases[i];    // [k][l], block-uniform

    // load 36 bf16 features (contiguous) via 5 x uint4
    union { uint4 q[5]; unsigned short s[40]; } hv;
    const unsigned short* hp = h7 + (size_t)(n * 16384 + h * 128 + w) * 64;
#pragma unroll
    for (int i = 0; i < 5; ++i) hv.q[i] = ((const uint4*)hp)[i];

    float coef[54];   // [m][l]
#pragma unroll
    for (int i = 0; i < 54; ++i) coef[i] = 0.f;
#pragma unroll
    for (int m = 0; m < 6; ++m)
#pragma unroll
        for (int k = 0; k < 6; ++k) {
            float f = us2f(hv.s[m * 6 + k]);
#pragma unroll
            for (int l = 0; l < 9; ++l)
                coef[m * 9 + l] = fmaf(f, bs[k * 9 + l], coef[m * 9 + l]);
        }

    float* op = out + (size_t)n * 384 * 16384 + h * 128 + w;

    for (int half = 0; half < 2; ++half) {
        if (half) __syncthreads();
        for (int idx = t; idx < 32 * 340; idx += 256) {
            int ci = idx / 340, r = idx % 340, y = r / 34, xw = r % 34;
            int gy = h0 + y - 1, gx = w0 + xw - 1;
            float v = 0.f;
            if ((unsigned)gy < 128u && (unsigned)gx < 128u)
                v = xp[(size_t)(half * 32 + ci) * 16384 + gy * 128 + gx];
            tile[idx] = v;
        }
        __syncthreads();

#pragma unroll 1
        for (int c = 0; c < 32; ++c) {
            float xv[9];
#pragma unroll
            for (int ky = 0; ky < 3; ++ky)
#pragma unroll
                for (int kx = 0; kx < 3; ++kx)
                    xv[ky * 3 + kx] = tile[c * 340 + (th + ky) * 34 + (tw + kx)];
            int cg = half * 32 + c;
#pragma unroll
            for (int m = 0; m < 6; ++m) {
                float s = 0.f;
#pragma unroll
                for (int l = 0; l < 9; ++l) s = fmaf(coef[m * 9 + l], xv[l], s);
                op[(size_t)(cg * 6 + m) * 16384] = s;
            }
        }
    }
}

// ---------------- launch -------------------------------------------------------
extern "C" void kernel_launch(void* const* d_in, const int* in_sizes, int n_in,
                              void* d_out, int out_size, void* d_ws, size_t ws_size,
                              hipStream_t stream)
{
    const float* x   = (const float*)d_in[0];
    const float* w0  = (const float*)d_in[1];
    const float* b0  = (const float*)d_in[2];
    const float* g0  = (const float*)d_in[3];
    const float* be0 = (const float*)d_in[4];
    const float* m0  = (const float*)d_in[5];
    const float* v0  = (const float*)d_in[6];
    const float* wm  = (const float*)d_in[7];
    const float* bm  = (const float*)d_in[8];
    const float* gm  = (const float*)d_in[9];
    const float* bem = (const float*)d_in[10];
    const float* mm  = (const float*)d_in[11];
    const float* vm  = (const float*)d_in[12];
    const float* wl  = (const float*)d_in[13];
    const float* bl  = (const float*)d_in[14];
    const float* gl  = (const float*)d_in[15];
    const float* bel = (const float*)d_in[16];
    const float* ml  = (const float*)d_in[17];
    const float* vl  = (const float*)d_in[18];
    const float* bas = (const float*)d_in[19];

    unsigned short* Wfb = (unsigned short*)d_ws;                    // 516096 B
    float* Af  = (float*)((char*)d_ws + 524288);                    // 448 floats
    float* Bf  = Af + 448;
    unsigned short* xcl  = (unsigned short*)((char*)d_ws + (size_t)(2  << 20));
    unsigned short* bufA = (unsigned short*)((char*)d_ws + (size_t)(2  << 20) + 16777216);
    unsigned short* bufB = (unsigned short*)((char*)d_ws + (size_t)(2  << 20) + 2 * 16777216);

    prep_x<<<1024, 256, 0, stream>>>(x, xcl);
    prep_wf<<<1008, 256, 0, stream>>>(w0, wm, wl, Wfb);
    prep_ab<<<2, 256, 0, stream>>>(b0, g0, be0, m0, v0,
                                   bm, gm, bem, mm, vm,
                                   bl, gl, bel, ml, vl, Af, Bf);

    dim3 cg(8, 8, 8);
    conv_mfma<<<cg, 256, 0, stream>>>(xcl,  Wfb + 0 * 36864, Af + 0,   Bf + 0,   bufA);
    conv_mfma<<<cg, 256, 0, stream>>>(bufA, Wfb + 1 * 36864, Af + 64,  Bf + 64,  bufB);
    conv_mfma<<<cg, 256, 0, stream>>>(bufB, Wfb + 2 * 36864, Af + 128, Bf + 128, bufA);
    conv_mfma<<<cg, 256, 0, stream>>>(bufA, Wfb + 3 * 36864, Af + 192, Bf + 192, bufB);
    conv_mfma<<<cg, 256, 0, stream>>>(bufB, Wfb + 4 * 36864, Af + 256, Bf + 256, bufA);
    conv_mfma<<<cg, 256, 0, stream>>>(bufA, Wfb + 5 * 36864, Af + 320, Bf + 320, bufB);
    conv_mfma<<<cg, 256, 0, stream>>>(bufB, Wfb + 6 * 36864, Af + 384, Bf + 384, bufA);

    dim3 dg(4, 16, 8);
    dyn_conv<<<dg, 256, 0, stream>>>(x, bufA, bas, (float*)d_out);
}